// Round 3
// baseline (501.922 us; speedup 1.0000x reference)
//
#include <hip/hip_runtime.h>

#define NB 8
#define NC 256
#define NN 1024
#define HD 32

// K1: qkv[b,o,n] = sum_c qkv_w[o,c] * x[b,c,n]   (fp32 in, fp32 out to ws)
// grid (48, 8), block 256. o-tile = 16, each thread owns 4 consecutive n.
__global__ void __launch_bounds__(256) k_qkv(const float* __restrict__ x,
                                             const float* __restrict__ w,
                                             float* __restrict__ qkv){
  const int b = blockIdx.y, o0 = blockIdx.x*16;
  const int tid = threadIdx.x;
  __shared__ float sw[16][260];            // pitch 260: rows 16B-aligned for float4 reads
  #pragma unroll
  for (int i = 0; i < 16; i++){
    int idx = tid + 256*i, j = idx>>8, c = idx&255;
    sw[j][c] = w[(o0+j)*NC + c];
  }
  __syncthreads();
  const int n0 = tid*4;
  const float* xb = x + b*NC*NN + n0;
  float acc[16][4];
  #pragma unroll
  for (int j=0;j<16;j++){acc[j][0]=0.f;acc[j][1]=0.f;acc[j][2]=0.f;acc[j][3]=0.f;}
  for (int c4 = 0; c4 < 64; c4++){
    float xv[4][4];
    #pragma unroll
    for (int cc = 0; cc < 4; cc++){
      float4 px = *(const float4*)(xb + (c4*4+cc)*NN);
      xv[cc][0]=px.x; xv[cc][1]=px.y; xv[cc][2]=px.z; xv[cc][3]=px.w;
    }
    #pragma unroll
    for (int j = 0; j < 16; j++){
      float4 wv = *(const float4*)&sw[j][c4*4];
      #pragma unroll
      for (int t = 0; t < 4; t++)
        acc[j][t] += wv.x*xv[0][t] + wv.y*xv[1][t] + wv.z*xv[2][t] + wv.w*xv[3][t];
    }
  }
  float* op = qkv + (b*768 + o0)*NN + n0;
  #pragma unroll
  for (int j = 0; j < 16; j++){
    float4 r; r.x=acc[j][0]; r.y=acc[j][1]; r.z=acc[j][2]; r.w=acc[j][3];
    *(float4*)(op + j*NN) = r;
  }
}

// K2: attention. lane = query. grid (8 qc, 8 h, 8 b), block 128 (2 waves).
// K/V chunk of 128 keys staged transposed [m][d] in LDS; per-lane fp32 state:
// qreg[32], num[32], den. No max-subtraction (|s| <= ~0.6, exp safe).
__global__ void __launch_bounds__(128) k_attn(const float* __restrict__ qkv,
                                              float* __restrict__ o){
  const int qc = blockIdx.x, h = blockIdx.y, b = blockIdx.z;
  const int tid = threadIdx.x;
  const int n = qc*128 + tid;               // this lane's query index
  const float* qb = qkv + (b*768 +       h*HD)*NN;
  const float* kb = qkv + (b*768 + 256 + h*HD)*NN;
  const float* vb = qkv + (b*768 + 512 + h*HD)*NN;
  float qreg[32];
  #pragma unroll
  for (int d = 0; d < 32; d++) qreg[d] = qb[d*NN + n] * 0.17677669529663689f;
  float num[32];
  #pragma unroll
  for (int d = 0; d < 32; d++) num[d] = 0.f;
  float den = 0.f;
  __shared__ float ks[128][36];             // pitch 36: rows 144B (16B-aligned)
  __shared__ float vs[128][36];
  for (int ch = 0; ch < 8; ch++){
    const int m0 = ch*128;
    __syncthreads();
    #pragma unroll
    for (int d = 0; d < 32; d++){           // coalesced global reads (m across lanes)
      ks[tid][d] = kb[d*NN + m0 + tid];
      vs[tid][d] = vb[d*NN + m0 + tid];
    }
    __syncthreads();
    #pragma unroll 2
    for (int m = 0; m < 128; m++){
      float s = 0.f;
      #pragma unroll
      for (int dq = 0; dq < 8; dq++){
        float4 kv = *(const float4*)&ks[m][dq*4];
        s += qreg[dq*4+0]*kv.x + qreg[dq*4+1]*kv.y + qreg[dq*4+2]*kv.z + qreg[dq*4+3]*kv.w;
      }
      float p = __builtin_amdgcn_exp2f(s * 1.4426950408889634f);
      den += p;
      #pragma unroll
      for (int dq = 0; dq < 8; dq++){
        float4 vv = *(const float4*)&vs[m][dq*4];
        num[dq*4+0] += p*vv.x; num[dq*4+1] += p*vv.y;
        num[dq*4+2] += p*vv.z; num[dq*4+3] += p*vv.w;
      }
    }
  }
  const float inv = 1.f / den;
  float* ob = o + (b*NC + h*HD)*NN + n;     // coalesced: lanes = consecutive n
  #pragma unroll
  for (int d = 0; d < 32; d++) ob[d*NN] = num[d]*inv;
}

// K3: t[b,c,n] += depthwise5x5(v)[b,c,n] + lepe_b[c].  grid (256, 8), block 256.
__global__ void __launch_bounds__(256) k_lepe(const float* __restrict__ qkv,
                                              const float* __restrict__ lw,
                                              const float* __restrict__ lb,
                                              float* __restrict__ t){
  const int c = blockIdx.x, b = blockIdx.y;
  const int tid = threadIdx.x;
  const float* vb = qkv + (b*768 + 512 + c)*NN;
  float wreg[25];
  #pragma unroll
  for (int i = 0; i < 25; i++) wreg[i] = lw[c*25 + i];
  const float bias = lb[c];
  float* tb = t + (b*NC + c)*NN;
  for (int r = 0; r < 4; r++){
    const int n = r*256 + tid;
    const int hh = n >> 5, ww = n & 31;
    float acc = bias;
    #pragma unroll
    for (int ky = 0; ky < 5; ky++){
      const int y = hh + ky - 2;
      if (y < 0 || y > 31) continue;
      #pragma unroll
      for (int kx = 0; kx < 5; kx++){
        const int xx = ww + kx - 2;
        if (xx < 0 || xx > 31) continue;
        acc += wreg[ky*5+kx] * vb[y*32 + xx];
      }
    }
    tb[n] += acc;
  }
}

// K4: out[b,o,n] = sum_c proj_w[o,c]*t[b,c,n] + proj_b[o]   (fp32 out)
// grid (32, 8): 16 o-tiles x 2 n-halves. block 256, 2 n per thread.
__global__ void __launch_bounds__(256) k_proj(const float* __restrict__ t,
                                              const float* __restrict__ pw,
                                              const float* __restrict__ pb,
                                              float* __restrict__ out){
  const int ot = blockIdx.x & 15, nh = blockIdx.x >> 4, b = blockIdx.y;
  const int o0 = ot*16;
  const int tid = threadIdx.x;
  __shared__ float sw[16][260];
  #pragma unroll
  for (int i = 0; i < 16; i++){
    int idx = tid + 256*i, j = idx>>8, c = idx&255;
    sw[j][c] = pw[(o0+j)*NC + c];
  }
  __syncthreads();
  const int n0 = nh*512 + tid*2;
  const float* tb = t + b*NC*NN + n0;
  float acc[16][2];
  #pragma unroll
  for (int j=0;j<16;j++){acc[j][0]=0.f;acc[j][1]=0.f;}
  for (int c4 = 0; c4 < 64; c4++){
    float xv[4][2];
    #pragma unroll
    for (int cc = 0; cc < 4; cc++){
      float2 px = *(const float2*)(tb + (c4*4+cc)*NN);
      xv[cc][0]=px.x; xv[cc][1]=px.y;
    }
    #pragma unroll
    for (int j = 0; j < 16; j++){
      float4 wv = *(const float4*)&sw[j][c4*4];
      #pragma unroll
      for (int tt = 0; tt < 2; tt++)
        acc[j][tt] += wv.x*xv[0][tt] + wv.y*xv[1][tt] + wv.z*xv[2][tt] + wv.w*xv[3][tt];
    }
  }
  float* ob = out + (b*NC + o0)*NN + n0;
  #pragma unroll
  for (int j = 0; j < 16; j++){
    const float bb = pb[o0+j];
    float2 r; r.x = acc[j][0]+bb; r.y = acc[j][1]+bb;
    *(float2*)(ob + j*NN) = r;
  }
}

extern "C" void kernel_launch(void* const* d_in, const int* in_sizes, int n_in,
                              void* d_out, int out_size, void* d_ws, size_t ws_size,
                              hipStream_t stream){
  const float* x      = (const float*)d_in[0];
  const float* qkv_w  = (const float*)d_in[1];
  const float* proj_w = (const float*)d_in[2];
  const float* proj_b = (const float*)d_in[3];
  const float* lepe_w = (const float*)d_in[4];
  const float* lepe_b = (const float*)d_in[5];
  float* out = (float*)d_out;

  // ws layout: qkv fp32 [8][768][1024] (25.17 MB) | t fp32 [8][256][1024] (8.39 MB)
  if (ws_size < (size_t)(NB*768*NN + NB*NC*NN) * sizeof(float)) return;
  float* qkv = (float*)d_ws;
  float* t   = qkv + NB*768*NN;

  k_qkv <<<dim3(48, 8),   256, 0, stream>>>(x, qkv_w, qkv);
  k_attn<<<dim3(8, 8, 8), 128, 0, stream>>>(qkv, t);
  k_lepe<<<dim3(256, 8),  256, 0, stream>>>(qkv, lepe_w, lepe_b, t);
  k_proj<<<dim3(32, 8),   256, 0, stream>>>(t, proj_w, proj_b, out);
}

// Round 4
// 200.774 us; speedup vs baseline: 2.4999x; 2.4999x over previous
//
#include <hip/hip_runtime.h>

#define NB 8
#define NC 256
#define NN 1024

typedef unsigned short u16;
typedef unsigned int u32;
typedef __attribute__((ext_vector_type(8))) short short8;
typedef __attribute__((ext_vector_type(4))) float f32x4;

__device__ __forceinline__ u16 f2b(float f){ union{float ff;u32 i;}v; v.ff = f; u32 r = v.i + 0x7FFFu + ((v.i>>16)&1u); return (u16)(r>>16); }
__device__ __forceinline__ float bitslo(u32 p){ union{u32 i;float f;}v; v.i = p<<16; return v.f; }
__device__ __forceinline__ float bitshi(u32 p){ union{u32 i;float f;}v; v.i = p & 0xFFFF0000u; return v.f; }

// fold SCALE (1/sqrt(32)) * log2(e) into stored q so softmax is exp2(q'.k)
#define QSC 0.25503486f

// K1: qkv GEMM, fp32 VALU. Writes q_t,k_t bf16 [b,h][n][32] and v bf16 [b,c][n].
// grid (96, 8): 48 o-tiles x 2 n-halves. block 256, 2 n per thread.
__global__ void __launch_bounds__(256) k_qkv(const float* __restrict__ x,
                                             const float* __restrict__ w,
                                             u16* __restrict__ qt,
                                             u16* __restrict__ kt,
                                             u16* __restrict__ vb){
  const int b = blockIdx.y;
  const int ot = blockIdx.x >> 1, nh = blockIdx.x & 1;
  const int o0 = ot*16;
  const int tid = threadIdx.x;
  __shared__ float sw[16][260];
  #pragma unroll
  for (int i = 0; i < 16; i++){
    int idx = tid + 256*i, j = idx>>8, c = idx&255;
    sw[j][c] = w[(o0+j)*NC + c];
  }
  __syncthreads();
  const int n0 = nh*512 + tid*2;
  const float* xb = x + b*NC*NN + n0;
  float acc[16][2];
  #pragma unroll
  for (int j=0;j<16;j++){acc[j][0]=0.f;acc[j][1]=0.f;}
  for (int c4 = 0; c4 < 64; c4++){
    float xv[4][2];
    #pragma unroll
    for (int cc = 0; cc < 4; cc++){
      float2 px = *(const float2*)(xb + (c4*4+cc)*NN);
      xv[cc][0]=px.x; xv[cc][1]=px.y;
    }
    #pragma unroll
    for (int j = 0; j < 16; j++){
      float4 wv = *(const float4*)&sw[j][c4*4];
      #pragma unroll
      for (int t = 0; t < 2; t++)
        acc[j][t] += wv.x*xv[0][t] + wv.y*xv[1][t] + wv.z*xv[2][t] + wv.w*xv[3][t];
    }
  }
  if (o0 < 256){                       // q -> q_t[b,h][n][d], pre-scaled
    const int h = o0>>5, d0 = o0&31;
    #pragma unroll
    for (int nn = 0; nn < 2; nn++){
      uint4 r0, r1;
      r0.x = (u32)f2b(acc[0][nn]*QSC) | ((u32)f2b(acc[1][nn]*QSC)<<16);
      r0.y = (u32)f2b(acc[2][nn]*QSC) | ((u32)f2b(acc[3][nn]*QSC)<<16);
      r0.z = (u32)f2b(acc[4][nn]*QSC) | ((u32)f2b(acc[5][nn]*QSC)<<16);
      r0.w = (u32)f2b(acc[6][nn]*QSC) | ((u32)f2b(acc[7][nn]*QSC)<<16);
      r1.x = (u32)f2b(acc[8][nn]*QSC) | ((u32)f2b(acc[9][nn]*QSC)<<16);
      r1.y = (u32)f2b(acc[10][nn]*QSC)| ((u32)f2b(acc[11][nn]*QSC)<<16);
      r1.z = (u32)f2b(acc[12][nn]*QSC)| ((u32)f2b(acc[13][nn]*QSC)<<16);
      r1.w = (u32)f2b(acc[14][nn]*QSC)| ((u32)f2b(acc[15][nn]*QSC)<<16);
      u16* dst = qt + ((size_t)(b*8+h)*NN + n0+nn)*32 + d0;
      *(uint4*)dst = r0; *(uint4*)(dst+8) = r1;
    }
  } else if (o0 < 512){                // k -> k_t[b,h][n][d]
    const int oo = o0-256, h = oo>>5, d0 = oo&31;
    #pragma unroll
    for (int nn = 0; nn < 2; nn++){
      uint4 r0, r1;
      r0.x = (u32)f2b(acc[0][nn]) | ((u32)f2b(acc[1][nn])<<16);
      r0.y = (u32)f2b(acc[2][nn]) | ((u32)f2b(acc[3][nn])<<16);
      r0.z = (u32)f2b(acc[4][nn]) | ((u32)f2b(acc[5][nn])<<16);
      r0.w = (u32)f2b(acc[6][nn]) | ((u32)f2b(acc[7][nn])<<16);
      r1.x = (u32)f2b(acc[8][nn]) | ((u32)f2b(acc[9][nn])<<16);
      r1.y = (u32)f2b(acc[10][nn])| ((u32)f2b(acc[11][nn])<<16);
      r1.z = (u32)f2b(acc[12][nn])| ((u32)f2b(acc[13][nn])<<16);
      r1.w = (u32)f2b(acc[14][nn])| ((u32)f2b(acc[15][nn])<<16);
      u16* dst = kt + ((size_t)(b*8+h)*NN + n0+nn)*32 + d0;
      *(uint4*)dst = r0; *(uint4*)(dst+8) = r1;
    }
  } else {                             // v -> v[b,c][n] (natural image layout)
    const int c0 = o0-512;
    #pragma unroll
    for (int j = 0; j < 16; j++){
      u32 pk = (u32)f2b(acc[j][0]) | ((u32)f2b(acc[j][1])<<16);
      *(u32*)(vb + (size_t)(b*256+c0+j)*NN + n0) = pk;
    }
  }
}

// K2: MFMA flash attention, no max-subtraction (|s|<=~0.8).
// Wave = 32 queries (2 x 16x16 tiles), chunk = 32 keys (one K=32 MFMA pass).
// grid (8, 8, 8) blocks of 256 (4 waves); each block covers 128 queries of (b,h).
__global__ void __launch_bounds__(256) k_attn(const u16* __restrict__ qt,
                                              const u16* __restrict__ kt,
                                              const u16* __restrict__ v,
                                              float* __restrict__ t){
  const int h = blockIdx.y, b = blockIdx.z;
  const int tid = threadIdx.x;
  const int wv = tid >> 6, lane = tid & 63;
  const int l15 = lane & 15, quad = lane >> 4;
  const int bh = b*8 + h;
  const int q0 = (blockIdx.x*4 + wv)*32;

  __shared__ u16 pb[4][2][16][40];     // per-wave P tiles; pitch 40 keeps 16B align
  u16* pbA = &pb[wv][0][0][0];
  u16* pbB = &pb[wv][1][0][0];

  union FR { uint4 u; short8 s; };

  const u16* qtb = qt + (size_t)bh*NN*32;
  const u16* ktb = kt + (size_t)bh*NN*32;
  const u16* vbp = v + (size_t)(b*256 + h*32)*NN;

  FR qa, qb_;
  qa.u  = *(const uint4*)(qtb + (size_t)(q0      + l15)*32 + quad*8);
  qb_.u = *(const uint4*)(qtb + (size_t)(q0 + 16 + l15)*32 + quad*8);

  f32x4 z = {0.f,0.f,0.f,0.f};
  f32x4 oA0 = z, oA1 = z, oB0 = z, oB1 = z;
  float denA[4] = {0.f,0.f,0.f,0.f}, denB[4] = {0.f,0.f,0.f,0.f};

  for (int m0 = 0; m0 < NN; m0 += 32){
    FR kf0, kf1, vf0, vf1;
    kf0.u = *(const uint4*)(ktb + (size_t)(m0      + l15)*32 + quad*8);
    kf1.u = *(const uint4*)(ktb + (size_t)(m0 + 16 + l15)*32 + quad*8);
    vf0.u = *(const uint4*)(vbp + (size_t)(l15     )*NN + m0 + quad*8);
    vf1.u = *(const uint4*)(vbp + (size_t)(16 + l15)*NN + m0 + quad*8);

    f32x4 sA0 = __builtin_amdgcn_mfma_f32_16x16x32_bf16(qa.s,  kf0.s, z, 0,0,0);
    f32x4 sA1 = __builtin_amdgcn_mfma_f32_16x16x32_bf16(qa.s,  kf1.s, z, 0,0,0);
    f32x4 sB0 = __builtin_amdgcn_mfma_f32_16x16x32_bf16(qb_.s, kf0.s, z, 0,0,0);
    f32x4 sB1 = __builtin_amdgcn_mfma_f32_16x16x32_bf16(qb_.s, kf1.s, z, 0,0,0);

    #pragma unroll
    for (int r = 0; r < 4; r++){
      float pA0 = __builtin_amdgcn_exp2f(sA0[r]);
      float pA1 = __builtin_amdgcn_exp2f(sA1[r]);
      float pB0 = __builtin_amdgcn_exp2f(sB0[r]);
      float pB1 = __builtin_amdgcn_exp2f(sB1[r]);
      denA[r] += pA0 + pA1;
      denB[r] += pB0 + pB1;
      const int row = (quad*4 + r)*40;
      pbA[row + l15]      = (u16)(__float_as_uint(pA0)>>16);  // bf16 truncate:
      pbA[row + 16 + l15] = (u16)(__float_as_uint(pA1)>>16);  // uniform bias cancels
      pbB[row + l15]      = (u16)(__float_as_uint(pB0)>>16);  // in the normalize
      pbB[row + 16 + l15] = (u16)(__float_as_uint(pB1)>>16);
    }
    FR pfA, pfB;                        // D-layout -> A-layout via LDS
    pfA.u = *(const uint4*)(pbA + l15*40 + quad*8);
    pfB.u = *(const uint4*)(pbB + l15*40 + quad*8);

    oA0 = __builtin_amdgcn_mfma_f32_16x16x32_bf16(pfA.s, vf0.s, oA0, 0,0,0);
    oA1 = __builtin_amdgcn_mfma_f32_16x16x32_bf16(pfA.s, vf1.s, oA1, 0,0,0);
    oB0 = __builtin_amdgcn_mfma_f32_16x16x32_bf16(pfB.s, vf0.s, oB0, 0,0,0);
    oB1 = __builtin_amdgcn_mfma_f32_16x16x32_bf16(pfB.s, vf1.s, oB1, 0,0,0);
  }
  #pragma unroll
  for (int r = 0; r < 4; r++){          // reduce den across the 16 lanes of each quad-row
    #pragma unroll
    for (int m = 1; m < 16; m <<= 1){
      denA[r] += __shfl_xor(denA[r], m);
      denB[r] += __shfl_xor(denB[r], m);
    }
  }
  float* tb = t + (size_t)(b*256 + h*32)*NN + q0;
  #pragma unroll
  for (int r = 0; r < 4; r++){
    const int q = quad*4 + r;
    const float iA = 1.f/denA[r], iB = 1.f/denB[r];
    tb[(size_t)(l15     )*NN + q]      = oA0[r]*iA;
    tb[(size_t)(16 + l15)*NN + q]      = oA1[r]*iA;
    tb[(size_t)(l15     )*NN + 16 + q] = oB0[r]*iB;
    tb[(size_t)(16 + l15)*NN + 16 + q] = oB1[r]*iB;
  }
}

// K3: t += depthwise5x5(v)+bias. v bf16, channel image staged in LDS.
__global__ void __launch_bounds__(256) k_lepe(const u16* __restrict__ v,
                                              const float* __restrict__ lw,
                                              const float* __restrict__ lb,
                                              float* __restrict__ t){
  const int c = blockIdx.x, b = blockIdx.y;
  const int tid = threadIdx.x;
  __shared__ float im[32][33];
  const u16* vbp = v + (size_t)(b*256+c)*NN;
  {
    const int row = tid>>3, col0 = (tid&7)*4;
    uint2 ld = *(const uint2*)(vbp + row*32 + col0);
    im[row][col0+0] = bitslo(ld.x); im[row][col0+1] = bitshi(ld.x);
    im[row][col0+2] = bitslo(ld.y); im[row][col0+3] = bitshi(ld.y);
  }
  __syncthreads();
  float wreg[25];
  #pragma unroll
  for (int i = 0; i < 25; i++) wreg[i] = lw[c*25 + i];
  const float bias = lb[c];
  float* tb = t + (size_t)(b*NC + c)*NN;
  for (int r = 0; r < 4; r++){
    const int n = r*256 + tid;
    const int hh = n >> 5, ww = n & 31;
    float acc = bias;
    #pragma unroll
    for (int ky = 0; ky < 5; ky++){
      const int y = hh + ky - 2;
      if (y < 0 || y > 31) continue;
      #pragma unroll
      for (int kx = 0; kx < 5; kx++){
        const int xx = ww + kx - 2;
        if (xx < 0 || xx > 31) continue;
        acc += wreg[ky*5+kx] * im[y][xx];
      }
    }
    tb[n] += acc;
  }
}

// K4: out = proj_w @ t + proj_b, fp32. grid (64,8): 16 o-tiles x 4 n-quarters, 1 n/thread.
__global__ void __launch_bounds__(256) k_proj(const float* __restrict__ t,
                                              const float* __restrict__ pw,
                                              const float* __restrict__ pb,
                                              float* __restrict__ out){
  const int ot = blockIdx.x >> 2, nq = blockIdx.x & 3, b = blockIdx.y;
  const int o0 = ot*16;
  const int tid = threadIdx.x;
  __shared__ float sw[16][260];
  #pragma unroll
  for (int i = 0; i < 16; i++){
    int idx = tid + 256*i, j = idx>>8, c = idx&255;
    sw[j][c] = pw[(o0+j)*NC + c];
  }
  __syncthreads();
  const int n0 = nq*256 + tid;
  const float* tb = t + b*NC*NN + n0;
  float acc[16];
  #pragma unroll
  for (int j=0;j<16;j++) acc[j]=0.f;
  for (int c4 = 0; c4 < 64; c4++){
    float xv[4];
    #pragma unroll
    for (int cc = 0; cc < 4; cc++) xv[cc] = tb[(c4*4+cc)*NN];
    #pragma unroll
    for (int j = 0; j < 16; j++){
      float4 wv = *(const float4*)&sw[j][c4*4];
      acc[j] += wv.x*xv[0] + wv.y*xv[1] + wv.z*xv[2] + wv.w*xv[3];
    }
  }
  #pragma unroll
  for (int j = 0; j < 16; j++)
    out[(size_t)(b*NC + o0+j)*NN + n0] = acc[j] + pb[o0+j];
}

extern "C" void kernel_launch(void* const* d_in, const int* in_sizes, int n_in,
                              void* d_out, int out_size, void* d_ws, size_t ws_size,
                              hipStream_t stream){
  const float* x      = (const float*)d_in[0];
  const float* qkv_w  = (const float*)d_in[1];
  const float* proj_w = (const float*)d_in[2];
  const float* proj_b = (const float*)d_in[3];
  const float* lepe_w = (const float*)d_in[4];
  const float* lepe_b = (const float*)d_in[5];
  float* out = (float*)d_out;

  // ws: qt bf16 4MB | kt bf16 4MB | v bf16 4MB | t fp32 8MB  (20MB total)
  if (ws_size < (size_t)20*1024*1024) return;
  u16* qt = (u16*)d_ws;
  u16* kt = qt + (size_t)NB*8*NN*32;
  u16* vb = kt + (size_t)NB*8*NN*32;
  float* t = (float*)(vb + (size_t)NB*NC*NN);

  k_qkv <<<dim3(96, 8),   256, 0, stream>>>(x, qkv_w, qt, kt, vb);
  k_attn<<<dim3(8, 8, 8), 256, 0, stream>>>(qt, kt, vb, t);
  k_lepe<<<dim3(256, 8),  256, 0, stream>>>(vb, lepe_w, lepe_b, t);
  k_proj<<<dim3(64, 8),   256, 0, stream>>>(t, proj_w, proj_b, out);
}

// Round 5
// 146.503 us; speedup vs baseline: 3.4260x; 1.3704x over previous
//
#include <hip/hip_runtime.h>

#define NB 8
#define NC 256
#define NN 1024

typedef unsigned short u16;
typedef unsigned int u32;
typedef __attribute__((ext_vector_type(8))) short short8;
typedef __attribute__((ext_vector_type(4))) float f32x4;

__device__ __forceinline__ u16 f2b(float f){ union{float ff;u32 i;}v; v.ff=f; u32 r=v.i+0x7FFFu+((v.i>>16)&1u); return (u16)(r>>16); }
__device__ __forceinline__ float b2f(u16 p){ union{u32 i;float f;}v; v.i=((u32)p)<<16; return v.f; }

// fold SCALE (1/sqrt(32)) * log2(e) into stored q so softmax is exp2(q'.k)
#define QSC 0.25503486f

union FR { uint4 u; short8 s; };

// W0: cast qkv_w (768x256) and proj_w (256x256) fp32 -> bf16, flat.
__global__ void __launch_bounds__(256) k_castw(const float* __restrict__ qkvw,
                                               const float* __restrict__ projw,
                                               u16* __restrict__ wb){
  const int idx = blockIdx.x*256 + threadIdx.x;            // 65536 float4 groups
  const float* src = (idx < 49152) ? (qkvw + (size_t)idx*4)
                                   : (projw + (size_t)(idx-49152)*4);
  float4 a = *(const float4*)src;
  uint2 o;
  o.x = (u32)f2b(a.x) | ((u32)f2b(a.y)<<16);
  o.y = (u32)f2b(a.z) | ((u32)f2b(a.w)<<16);
  *(uint2*)(wb + (size_t)idx*4) = o;
}

// W1: x[b,c,n] fp32 -> xt[b,n,c] bf16 (LDS tile transpose).
// grid (16 n-tiles, 2 c-halves, 8 b), block 256.
__global__ void __launch_bounds__(256) k_castx(const float* __restrict__ x,
                                               u16* __restrict__ xt){
  const int n0 = blockIdx.x*64, c0 = blockIdx.y*128, b = blockIdx.z;
  const int tid = threadIdx.x;
  __shared__ u16 lt[64][136];                 // [n][c] bf16; pitch 272B (16B mult)
  #pragma unroll
  for (int cc = 0; cc < 4; cc++){
    const int c = c0 + cc*32 + (tid>>3);
    const int ns = (tid&7)*8;
    const float* src = x + ((size_t)(b*NC + c))*NN + n0 + ns;
    float4 a = *(const float4*)src;
    float4 d = *(const float4*)(src+4);
    const int cl = c - c0;
    lt[ns+0][cl] = f2b(a.x); lt[ns+1][cl] = f2b(a.y);
    lt[ns+2][cl] = f2b(a.z); lt[ns+3][cl] = f2b(a.w);
    lt[ns+4][cl] = f2b(d.x); lt[ns+5][cl] = f2b(d.y);
    lt[ns+6][cl] = f2b(d.z); lt[ns+7][cl] = f2b(d.w);
  }
  __syncthreads();
  #pragma unroll
  for (int p = 0; p < 4; p++){
    const int flat = p*256 + tid;
    const int row = flat >> 4, seg = flat & 15;
    uint4 d = *(uint4*)&lt[row][seg*8];
    *(uint4*)(xt + ((size_t)(b*NN + n0 + row))*NC + c0 + seg*8) = d;
  }
}

// K2: qkv = Wqkv @ x via MFMA. grid (24 o-tiles of 32, 4 n-tiles of 256, 8 b),
// block 256 = 4 waves; wave = 32o x 64n. Outputs:
//   ot 0-7  : q -> qt[b,h][n][32] bf16, scaled by QSC (LDS repack)
//   ot 8-15 : k -> kt[b,h][n][32] bf16
//   ot 16-23: v -> v[b,c][n] bf16 (direct) AND vt[b,n][c] bf16 (repack)
__global__ void __launch_bounds__(256) k_qkv(const u16* __restrict__ wqb,
                                             const u16* __restrict__ xt,
                                             u16* __restrict__ qt,
                                             u16* __restrict__ kt,
                                             u16* __restrict__ v,
                                             u16* __restrict__ vt){
  const int ot = blockIdx.x, nt = blockIdx.y, b = blockIdx.z;
  const int o0 = ot*32;
  const int tid = threadIdx.x, wv = tid>>6, lane = tid&63;
  const int l15 = lane&15, quad = lane>>4;
  const int n0w = nt*256 + wv*64;
  __shared__ u16 swq[32][264];                 // A tile; pitch 528B (16B mult)
  __shared__ u16 s2[4][64][40];                // per-wave repack; pitch 80B
  #pragma unroll
  for (int i = 0; i < 4; i++){
    const int flat = i*256 + tid;
    const int row = flat >> 5, col = flat & 31;
    *(uint4*)&swq[row][col*8] = *(const uint4*)(wqb + (size_t)(o0+row)*NC + col*8);
  }
  __syncthreads();
  f32x4 acc[2][4];
  #pragma unroll
  for (int mt = 0; mt < 2; mt++)
    #pragma unroll
    for (int nt2 = 0; nt2 < 4; nt2++) acc[mt][nt2] = (f32x4){0.f,0.f,0.f,0.f};
  const u16* xb = xt + ((size_t)(b*NN + n0w))*NC;
  for (int k0 = 0; k0 < 256; k0 += 32){
    FR af[2], bf[4];
    af[0].u = *(uint4*)&swq[l15][k0 + quad*8];
    af[1].u = *(uint4*)&swq[16+l15][k0 + quad*8];
    #pragma unroll
    for (int nt2 = 0; nt2 < 4; nt2++)
      bf[nt2].u = *(const uint4*)(xb + (size_t)(nt2*16+l15)*NC + k0 + quad*8);
    #pragma unroll
    for (int mt = 0; mt < 2; mt++)
      #pragma unroll
      for (int nt2 = 0; nt2 < 4; nt2++)
        acc[mt][nt2] = __builtin_amdgcn_mfma_f32_16x16x32_bf16(af[mt].s, bf[nt2].s, acc[mt][nt2], 0,0,0);
  }
  if (ot < 16){                       // q/k: repack D (row=o,col=n) -> [n][o]
    const float sc = (ot < 8) ? QSC : 1.0f;
    u16* dstbase = (ot < 8) ? qt : kt;
    const int h = (ot < 8) ? ot : ot-8;
    #pragma unroll
    for (int mt = 0; mt < 2; mt++)
      #pragma unroll
      for (int nt2 = 0; nt2 < 4; nt2++){
        uint2 w;
        w.x = (u32)f2b(acc[mt][nt2][0]*sc) | ((u32)f2b(acc[mt][nt2][1]*sc)<<16);
        w.y = (u32)f2b(acc[mt][nt2][2]*sc) | ((u32)f2b(acc[mt][nt2][3]*sc)<<16);
        *(uint2*)&s2[wv][nt2*16+l15][mt*16+quad*4] = w;
      }
    __syncthreads();
    u16* db = dstbase + ((size_t)(b*8+h)*NN + n0w)*32;
    #pragma unroll
    for (int p = 0; p < 4; p++){
      const int n_loc = p*16 + (lane>>2), seg = lane&3;
      uint4 d = *(uint4*)&s2[wv][n_loc][seg*8];
      *(uint4*)(db + (size_t)n_loc*32 + seg*8) = d;
    }
  } else {                            // v: direct [c][n] + repack [n][c]
    const int c0 = o0 - 512;
    #pragma unroll
    for (int mt = 0; mt < 2; mt++)
      #pragma unroll
      for (int nt2 = 0; nt2 < 4; nt2++){
        #pragma unroll
        for (int r = 0; r < 4; r++)
          v[(size_t)(b*NC + c0 + mt*16 + quad*4 + r)*NN + n0w + nt2*16 + l15] = f2b(acc[mt][nt2][r]);
        uint2 w;
        w.x = (u32)f2b(acc[mt][nt2][0]) | ((u32)f2b(acc[mt][nt2][1])<<16);
        w.y = (u32)f2b(acc[mt][nt2][2]) | ((u32)f2b(acc[mt][nt2][3])<<16);
        *(uint2*)&s2[wv][nt2*16+l15][mt*16+quad*4] = w;
      }
    __syncthreads();
    u16* db = vt + ((size_t)(b*NN + n0w))*NC + c0;
    #pragma unroll
    for (int p = 0; p < 4; p++){
      const int n_loc = p*16 + (lane>>2), seg = lane&3;
      uint4 d = *(uint4*)&s2[wv][n_loc][seg*8];
      *(uint4*)(db + (size_t)n_loc*NC + seg*8) = d;
    }
  }
}

// K3: MFMA flash attention (core as R4). Writes tt[b,n,c] bf16.
__global__ void __launch_bounds__(256) k_attn(const u16* __restrict__ qt,
                                              const u16* __restrict__ kt,
                                              const u16* __restrict__ v,
                                              u16* __restrict__ tt){
  const int h = blockIdx.y, b = blockIdx.z;
  const int tid = threadIdx.x;
  const int wv = tid >> 6, lane = tid & 63;
  const int l15 = lane & 15, quad = lane >> 4;
  const int bh = b*8 + h;
  const int q0 = (blockIdx.x*4 + wv)*32;

  __shared__ u16 pb[4][2][16][40];
  u16* pbA = &pb[wv][0][0][0];
  u16* pbB = &pb[wv][1][0][0];

  const u16* qtb = qt + (size_t)bh*NN*32;
  const u16* ktb = kt + (size_t)bh*NN*32;
  const u16* vbp = v + (size_t)(b*256 + h*32)*NN;

  FR qa, qb_;
  qa.u  = *(const uint4*)(qtb + (size_t)(q0      + l15)*32 + quad*8);
  qb_.u = *(const uint4*)(qtb + (size_t)(q0 + 16 + l15)*32 + quad*8);

  f32x4 z = {0.f,0.f,0.f,0.f};
  f32x4 oA0 = z, oA1 = z, oB0 = z, oB1 = z;
  float denA[4] = {0.f,0.f,0.f,0.f}, denB[4] = {0.f,0.f,0.f,0.f};

  for (int m0 = 0; m0 < NN; m0 += 32){
    FR kf0, kf1, vf0, vf1;
    kf0.u = *(const uint4*)(ktb + (size_t)(m0      + l15)*32 + quad*8);
    kf1.u = *(const uint4*)(ktb + (size_t)(m0 + 16 + l15)*32 + quad*8);
    vf0.u = *(const uint4*)(vbp + (size_t)(l15     )*NN + m0 + quad*8);
    vf1.u = *(const uint4*)(vbp + (size_t)(16 + l15)*NN + m0 + quad*8);

    f32x4 sA0 = __builtin_amdgcn_mfma_f32_16x16x32_bf16(qa.s,  kf0.s, z, 0,0,0);
    f32x4 sA1 = __builtin_amdgcn_mfma_f32_16x16x32_bf16(qa.s,  kf1.s, z, 0,0,0);
    f32x4 sB0 = __builtin_amdgcn_mfma_f32_16x16x32_bf16(qb_.s, kf0.s, z, 0,0,0);
    f32x4 sB1 = __builtin_amdgcn_mfma_f32_16x16x32_bf16(qb_.s, kf1.s, z, 0,0,0);

    #pragma unroll
    for (int r = 0; r < 4; r++){
      float pA0 = __builtin_amdgcn_exp2f(sA0[r]);
      float pA1 = __builtin_amdgcn_exp2f(sA1[r]);
      float pB0 = __builtin_amdgcn_exp2f(sB0[r]);
      float pB1 = __builtin_amdgcn_exp2f(sB1[r]);
      denA[r] += pA0 + pA1;
      denB[r] += pB0 + pB1;
      const int row = (quad*4 + r)*40;
      pbA[row + l15]      = (u16)(__float_as_uint(pA0)>>16);
      pbA[row + 16 + l15] = (u16)(__float_as_uint(pA1)>>16);
      pbB[row + l15]      = (u16)(__float_as_uint(pB0)>>16);
      pbB[row + 16 + l15] = (u16)(__float_as_uint(pB1)>>16);
    }
    FR pfA, pfB;
    pfA.u = *(const uint4*)(pbA + l15*40 + quad*8);
    pfB.u = *(const uint4*)(pbB + l15*40 + quad*8);

    oA0 = __builtin_amdgcn_mfma_f32_16x16x32_bf16(pfA.s, vf0.s, oA0, 0,0,0);
    oA1 = __builtin_amdgcn_mfma_f32_16x16x32_bf16(pfA.s, vf1.s, oA1, 0,0,0);
    oB0 = __builtin_amdgcn_mfma_f32_16x16x32_bf16(pfB.s, vf0.s, oB0, 0,0,0);
    oB1 = __builtin_amdgcn_mfma_f32_16x16x32_bf16(pfB.s, vf1.s, oB1, 0,0,0);
  }
  #pragma unroll
  for (int r = 0; r < 4; r++){
    #pragma unroll
    for (int m = 1; m < 16; m <<= 1){
      denA[r] += __shfl_xor(denA[r], m);
      denB[r] += __shfl_xor(denB[r], m);
    }
  }
  u16* tb = tt + ((size_t)(b*NN + q0))*NC + h*32;
  #pragma unroll
  for (int r = 0; r < 4; r++){
    const int q = quad*4 + r;
    const float iA = 1.f/denA[r], iB = 1.f/denB[r];
    tb[(size_t)q*NC + l15]           = f2b(oA0[r]*iA);
    tb[(size_t)q*NC + 16 + l15]      = f2b(oA1[r]*iA);
    tb[(size_t)(q+16)*NC + l15]      = f2b(oB0[r]*iB);
    tb[(size_t)(q+16)*NC + 16 + l15] = f2b(oB1[r]*iB);
  }
}

// K4: lepe depthwise 5x5 + bias, RMW into tt[b,n,c]. lanes = channels.
// grid (128 n-tiles of 8, 8 b), block 256 (tid = c).
__global__ void __launch_bounds__(256) k_lepe(const u16* __restrict__ vt,
                                              const float* __restrict__ lw,
                                              const float* __restrict__ lb,
                                              u16* __restrict__ tt){
  const int b = blockIdx.y, c = threadIdx.x;
  const int n0 = blockIdx.x*8;
  const int y = n0 >> 5, x0 = n0 & 31;
  float wreg[25];
  #pragma unroll
  for (int i = 0; i < 25; i++) wreg[i] = lw[c*25+i];
  const float bias = lb[c];
  const u16* vb = vt + (size_t)(b*NN)*NC + c;
  u16* tb = tt + (size_t)(b*NN + n0)*NC + c;
  #pragma unroll
  for (int i = 0; i < 8; i++){
    float acc = bias;
    #pragma unroll
    for (int ky = 0; ky < 5; ky++){
      const int yy = y + ky - 2;
      if (yy < 0 || yy > 31) continue;
      #pragma unroll
      for (int kx = 0; kx < 5; kx++){
        const int xx = x0 + i + kx - 2;
        if (xx < 0 || xx > 31) continue;
        acc += wreg[ky*5+kx] * b2f(vb[(size_t)(yy*32+xx)*NC]);
      }
    }
    tb[(size_t)i*NC] = f2b(b2f(tb[(size_t)i*NC]) + acc);
  }
}

// K5: out = Wp @ t + bias via MFMA, B-frags direct from tt[b,n,c] bf16.
// grid (8 o-tiles of 32, 4 n-tiles of 256, 8 b), block 256 = 4 waves.
__global__ void __launch_bounds__(256) k_proj(const u16* __restrict__ wpb,
                                              const u16* __restrict__ tt,
                                              const float* __restrict__ pbias,
                                              float* __restrict__ out){
  const int ot = blockIdx.x, nt = blockIdx.y, b = blockIdx.z;
  const int o0 = ot*32;
  const int tid = threadIdx.x, wv = tid>>6, lane = tid&63;
  const int l15 = lane&15, quad = lane>>4;
  const int n0w = nt*256 + wv*64;
  __shared__ u16 swp[32][264];
  #pragma unroll
  for (int i = 0; i < 4; i++){
    const int flat = i*256 + tid;
    const int row = flat >> 5, col = flat & 31;
    *(uint4*)&swp[row][col*8] = *(const uint4*)(wpb + (size_t)(o0+row)*NC + col*8);
  }
  __syncthreads();
  f32x4 acc[2][4];
  #pragma unroll
  for (int mt = 0; mt < 2; mt++)
    #pragma unroll
    for (int nt2 = 0; nt2 < 4; nt2++) acc[mt][nt2] = (f32x4){0.f,0.f,0.f,0.f};
  const u16* tb = tt + ((size_t)(b*NN + n0w))*NC;
  for (int k0 = 0; k0 < 256; k0 += 32){
    FR af[2], bf[4];
    af[0].u = *(uint4*)&swp[l15][k0 + quad*8];
    af[1].u = *(uint4*)&swp[16+l15][k0 + quad*8];
    #pragma unroll
    for (int nt2 = 0; nt2 < 4; nt2++)
      bf[nt2].u = *(const uint4*)(tb + (size_t)(nt2*16+l15)*NC + k0 + quad*8);
    #pragma unroll
    for (int mt = 0; mt < 2; mt++)
      #pragma unroll
      for (int nt2 = 0; nt2 < 4; nt2++)
        acc[mt][nt2] = __builtin_amdgcn_mfma_f32_16x16x32_bf16(af[mt].s, bf[nt2].s, acc[mt][nt2], 0,0,0);
  }
  float bv[2][4];
  #pragma unroll
  for (int mt = 0; mt < 2; mt++)
    #pragma unroll
    for (int r = 0; r < 4; r++) bv[mt][r] = pbias[o0 + mt*16 + quad*4 + r];
  #pragma unroll
  for (int mt = 0; mt < 2; mt++)
    #pragma unroll
    for (int nt2 = 0; nt2 < 4; nt2++)
      #pragma unroll
      for (int r = 0; r < 4; r++)
        out[(size_t)(b*NC + o0 + mt*16 + quad*4 + r)*NN + n0w + nt2*16 + l15] = acc[mt][nt2][r] + bv[mt][r];
}

extern "C" void kernel_launch(void* const* d_in, const int* in_sizes, int n_in,
                              void* d_out, int out_size, void* d_ws, size_t ws_size,
                              hipStream_t stream){
  const float* x      = (const float*)d_in[0];
  const float* qkv_w  = (const float*)d_in[1];
  const float* proj_w = (const float*)d_in[2];
  const float* proj_b = (const float*)d_in[3];
  const float* lepe_w = (const float*)d_in[4];
  const float* lepe_b = (const float*)d_in[5];
  float* out = (float*)d_out;

  // ws (u16 units): wqb 196608 | wpb 65536 | xt 2M | qt 2M | kt 2M | v 2M | vt 2M | tt 2M
  if (ws_size < (size_t)25690112) return;
  u16* wqb = (u16*)d_ws;
  u16* wpb = wqb + 196608;
  u16* xt  = wpb + 65536;
  u16* qt  = xt + 2097152;
  u16* kt  = qt + 2097152;
  u16* v   = kt + 2097152;
  u16* vt  = v  + 2097152;
  u16* tt  = vt + 2097152;

  k_castw<<<dim3(256),      256, 0, stream>>>(qkv_w, proj_w, wqb);
  k_castx<<<dim3(16, 2, 8), 256, 0, stream>>>(x, xt);
  k_qkv  <<<dim3(24, 4, 8), 256, 0, stream>>>(wqb, xt, qt, kt, v, vt);
  k_attn <<<dim3(8, 8, 8),  256, 0, stream>>>(qt, kt, v, tt);
  k_lepe <<<dim3(128, 8),   256, 0, stream>>>(vt, lepe_w, lepe_b, tt);
  k_proj <<<dim3(8, 4, 8),  256, 0, stream>>>(wpb, tt, proj_b, out);
}

// Round 6
// 121.832 us; speedup vs baseline: 4.1198x; 1.2025x over previous
//
#include <hip/hip_runtime.h>

#define NB 8
#define NC 256
#define NN 1024

typedef unsigned short u16;
typedef unsigned int u32;
typedef __attribute__((ext_vector_type(8))) short short8;
typedef __attribute__((ext_vector_type(4))) float f32x4;

__device__ __forceinline__ u16 f2b(float f){ union{float ff;u32 i;}v; v.ff=f; u32 r=v.i+0x7FFFu+((v.i>>16)&1u); return (u16)(r>>16); }
__device__ __forceinline__ float b2f(u16 p){ union{u32 i;float f;}v; v.i=((u32)p)<<16; return v.f; }
__device__ __forceinline__ float pklo(u32 p){ union{u32 i;float f;}v; v.i=p<<16; return v.f; }
__device__ __forceinline__ float pkhi(u32 p){ union{u32 i;float f;}v; v.i=p&0xFFFF0000u; return v.f; }

// fold SCALE (1/sqrt(32)) * log2(e) into stored q so softmax is exp2(q'.k)
#define QSC 0.25503486f

union FR { uint4 u; short8 s; };

// K1: merged casts. Blocks 0..255: qkv_w+proj_w fp32->bf16 flat.
// Blocks 256..511: x[b,c,n] fp32 -> xt[b,n,c] bf16 (LDS tile transpose).
__global__ void __launch_bounds__(256) k_cast(const float* __restrict__ qkvw,
                                              const float* __restrict__ projw,
                                              const float* __restrict__ x,
                                              u16* __restrict__ wb,
                                              u16* __restrict__ xt){
  __shared__ u16 lt[64][136];
  const int tid = threadIdx.x;
  if (blockIdx.x < 256){
    const int idx = blockIdx.x*256 + tid;              // 65536 float4 groups
    const float* src = (idx < 49152) ? (qkvw + (size_t)idx*4)
                                     : (projw + (size_t)(idx-49152)*4);
    float4 a = *(const float4*)src;
    uint2 o;
    o.x = (u32)f2b(a.x) | ((u32)f2b(a.y)<<16);
    o.y = (u32)f2b(a.z) | ((u32)f2b(a.w)<<16);
    *(uint2*)(wb + (size_t)idx*4) = o;
    return;
  }
  const int bx = blockIdx.x - 256;
  const int n0 = (bx & 15)*64, c0 = ((bx>>4)&1)*128, b = bx>>5;
  #pragma unroll
  for (int cc = 0; cc < 4; cc++){
    const int c = c0 + cc*32 + (tid>>3);
    const int ns = (tid&7)*8;
    const float* src = x + ((size_t)(b*NC + c))*NN + n0 + ns;
    float4 a = *(const float4*)src;
    float4 d = *(const float4*)(src+4);
    const int cl = c - c0;
    lt[ns+0][cl] = f2b(a.x); lt[ns+1][cl] = f2b(a.y);
    lt[ns+2][cl] = f2b(a.z); lt[ns+3][cl] = f2b(a.w);
    lt[ns+4][cl] = f2b(d.x); lt[ns+5][cl] = f2b(d.y);
    lt[ns+6][cl] = f2b(d.z); lt[ns+7][cl] = f2b(d.w);
  }
  __syncthreads();
  #pragma unroll
  for (int p = 0; p < 4; p++){
    const int flat = p*256 + tid;
    const int row = flat >> 4, seg = flat & 15;
    uint4 d = *(uint4*)&lt[row][seg*8];
    *(uint4*)(xt + ((size_t)(b*NN + n0 + row))*NC + c0 + seg*8) = d;
  }
}

// K2: qkv = Wqkv @ x via MFMA. grid (24,4,8), block 256 = 4 waves of 32o x 64n.
//   ot 0-7  : q -> qt[b,h][n][32] bf16 (scaled by QSC), LDS repack
//   ot 8-15 : k -> kt[b,h][n][32] bf16
//   ot 16-23: v -> v[b,c][n] bf16 (direct scalar stores)
__global__ void __launch_bounds__(256) k_qkv(const u16* __restrict__ wqb,
                                             const u16* __restrict__ xt,
                                             u16* __restrict__ qt,
                                             u16* __restrict__ kt,
                                             u16* __restrict__ v){
  const int ot = blockIdx.x, nt = blockIdx.y, b = blockIdx.z;
  const int o0 = ot*32;
  const int tid = threadIdx.x, wv = tid>>6, lane = tid&63;
  const int l15 = lane&15, quad = lane>>4;
  const int n0w = nt*256 + wv*64;
  __shared__ u16 swq[32][264];
  __shared__ u16 s2[4][64][40];
  #pragma unroll
  for (int i = 0; i < 4; i++){
    const int flat = i*256 + tid;
    const int row = flat >> 5, col = flat & 31;
    *(uint4*)&swq[row][col*8] = *(const uint4*)(wqb + (size_t)(o0+row)*NC + col*8);
  }
  __syncthreads();
  f32x4 acc[2][4];
  #pragma unroll
  for (int mt = 0; mt < 2; mt++)
    #pragma unroll
    for (int nt2 = 0; nt2 < 4; nt2++) acc[mt][nt2] = (f32x4){0.f,0.f,0.f,0.f};
  const u16* xb = xt + ((size_t)(b*NN + n0w))*NC;
  for (int k0 = 0; k0 < 256; k0 += 32){
    FR af[2], bf[4];
    af[0].u = *(uint4*)&swq[l15][k0 + quad*8];
    af[1].u = *(uint4*)&swq[16+l15][k0 + quad*8];
    #pragma unroll
    for (int nt2 = 0; nt2 < 4; nt2++)
      bf[nt2].u = *(const uint4*)(xb + (size_t)(nt2*16+l15)*NC + k0 + quad*8);
    #pragma unroll
    for (int mt = 0; mt < 2; mt++)
      #pragma unroll
      for (int nt2 = 0; nt2 < 4; nt2++)
        acc[mt][nt2] = __builtin_amdgcn_mfma_f32_16x16x32_bf16(af[mt].s, bf[nt2].s, acc[mt][nt2], 0,0,0);
  }
  if (ot < 16){                       // q/k: repack D (row=o,col=n) -> [n][o]
    const float sc = (ot < 8) ? QSC : 1.0f;
    u16* dstbase = (ot < 8) ? qt : kt;
    const int h = (ot < 8) ? ot : ot-8;
    #pragma unroll
    for (int mt = 0; mt < 2; mt++)
      #pragma unroll
      for (int nt2 = 0; nt2 < 4; nt2++){
        uint2 w;
        w.x = (u32)f2b(acc[mt][nt2][0]*sc) | ((u32)f2b(acc[mt][nt2][1]*sc)<<16);
        w.y = (u32)f2b(acc[mt][nt2][2]*sc) | ((u32)f2b(acc[mt][nt2][3]*sc)<<16);
        *(uint2*)&s2[wv][nt2*16+l15][mt*16+quad*4] = w;
      }
    __syncthreads();
    u16* db = dstbase + ((size_t)(b*8+h)*NN + n0w)*32;
    #pragma unroll
    for (int p = 0; p < 4; p++){
      const int n_loc = p*16 + (lane>>2), seg = lane&3;
      uint4 d = *(uint4*)&s2[wv][n_loc][seg*8];
      *(uint4*)(db + (size_t)n_loc*32 + seg*8) = d;
    }
  } else {                            // v: direct [c][n] scalar stores
    const int c0 = o0 - 512;
    #pragma unroll
    for (int mt = 0; mt < 2; mt++)
      #pragma unroll
      for (int nt2 = 0; nt2 < 4; nt2++)
        #pragma unroll
        for (int r = 0; r < 4; r++)
          v[(size_t)(b*NC + c0 + mt*16 + quad*4 + r)*NN + n0w + nt2*16 + l15] = f2b(acc[mt][nt2][r]);
  }
}

// K3: MFMA flash attention + fused LePE. Writes tt[b,n,c] bf16.
// Block = 4 waves; wave wv covers image row y = blockIdx.x*4+wv (32 queries),
// channels h*32..h*32+31. LePE halo rows y0-2..y0+5 staged in vstage.
__global__ void __launch_bounds__(256) k_attn(const u16* __restrict__ qt,
                                              const u16* __restrict__ kt,
                                              const u16* __restrict__ v,
                                              const float* __restrict__ lw,
                                              const float* __restrict__ lb,
                                              u16* __restrict__ tt){
  const int h = blockIdx.y, b = blockIdx.z;
  const int tid = threadIdx.x;
  const int wv = tid >> 6, lane = tid & 63;
  const int l15 = lane & 15, quad = lane >> 4;
  const int bh = b*8 + h;
  const int q0 = (blockIdx.x*4 + wv)*32;

  __shared__ u16 pb[4][2][16][40];     // P round-trip
  __shared__ u16 vstage[8][32][38];    // [row][c][col]; pitch 38 hw: c-stride 19 dw (conflict-free)
  __shared__ u16 s_out[4][32][36];     // attn out tile [q][c]; pitch 36 (conflict-free writes)
  u16* pbA = &pb[wv][0][0][0];
  u16* pbB = &pb[wv][1][0][0];

  // --- stage LePE halo: rows y0-2..y0+5 of v for this head's 32 channels
  {
    const int rr = tid >> 5, lc2 = tid & 31;
    const int yy = blockIdx.x*4 - 2 + rr;
    u32* dst32 = (u32*)&vstage[rr][lc2][0];
    if (yy < 0 || yy > 31){
      #pragma unroll
      for (int j = 0; j < 19; j++) dst32[j] = 0;
    } else {
      const u16* src = v + ((size_t)(b*NC + h*32 + lc2))*NN + yy*32;
      uint4 a = *(const uint4*)src;
      uint4 b4 = *(const uint4*)(src+8);
      uint4 c4 = *(const uint4*)(src+16);
      uint4 d4 = *(const uint4*)(src+24);
      dst32[0] = 0;
      dst32[1]=a.x;  dst32[2]=a.y;  dst32[3]=a.z;  dst32[4]=a.w;
      dst32[5]=b4.x; dst32[6]=b4.y; dst32[7]=b4.z; dst32[8]=b4.w;
      dst32[9]=c4.x; dst32[10]=c4.y; dst32[11]=c4.z; dst32[12]=c4.w;
      dst32[13]=d4.x; dst32[14]=d4.y; dst32[15]=d4.z; dst32[16]=d4.w;
      dst32[17]=0; dst32[18]=0;
    }
  }
  __syncthreads();

  const u16* qtb = qt + (size_t)bh*NN*32;
  const u16* ktb = kt + (size_t)bh*NN*32;
  const u16* vbp = v + (size_t)(b*256 + h*32)*NN;

  FR qa, qb_;
  qa.u  = *(const uint4*)(qtb + (size_t)(q0      + l15)*32 + quad*8);
  qb_.u = *(const uint4*)(qtb + (size_t)(q0 + 16 + l15)*32 + quad*8);

  f32x4 z = {0.f,0.f,0.f,0.f};
  f32x4 oA0 = z, oA1 = z, oB0 = z, oB1 = z;
  float denA[4] = {0.f,0.f,0.f,0.f}, denB[4] = {0.f,0.f,0.f,0.f};

  for (int m0 = 0; m0 < NN; m0 += 32){
    FR kf0, kf1, vf0, vf1;
    kf0.u = *(const uint4*)(ktb + (size_t)(m0      + l15)*32 + quad*8);
    kf1.u = *(const uint4*)(ktb + (size_t)(m0 + 16 + l15)*32 + quad*8);
    vf0.u = *(const uint4*)(vbp + (size_t)(l15     )*NN + m0 + quad*8);
    vf1.u = *(const uint4*)(vbp + (size_t)(16 + l15)*NN + m0 + quad*8);

    f32x4 sA0 = __builtin_amdgcn_mfma_f32_16x16x32_bf16(qa.s,  kf0.s, z, 0,0,0);
    f32x4 sA1 = __builtin_amdgcn_mfma_f32_16x16x32_bf16(qa.s,  kf1.s, z, 0,0,0);
    f32x4 sB0 = __builtin_amdgcn_mfma_f32_16x16x32_bf16(qb_.s, kf0.s, z, 0,0,0);
    f32x4 sB1 = __builtin_amdgcn_mfma_f32_16x16x32_bf16(qb_.s, kf1.s, z, 0,0,0);

    #pragma unroll
    for (int r = 0; r < 4; r++){
      float pA0 = __builtin_amdgcn_exp2f(sA0[r]);
      float pA1 = __builtin_amdgcn_exp2f(sA1[r]);
      float pB0 = __builtin_amdgcn_exp2f(sB0[r]);
      float pB1 = __builtin_amdgcn_exp2f(sB1[r]);
      denA[r] += pA0 + pA1;
      denB[r] += pB0 + pB1;
      const int row = (quad*4 + r)*40;
      pbA[row + l15]      = (u16)(__float_as_uint(pA0)>>16);
      pbA[row + 16 + l15] = (u16)(__float_as_uint(pA1)>>16);
      pbB[row + l15]      = (u16)(__float_as_uint(pB0)>>16);
      pbB[row + 16 + l15] = (u16)(__float_as_uint(pB1)>>16);
    }
    FR pfA, pfB;
    pfA.u = *(const uint4*)(pbA + l15*40 + quad*8);
    pfB.u = *(const uint4*)(pbB + l15*40 + quad*8);

    oA0 = __builtin_amdgcn_mfma_f32_16x16x32_bf16(pfA.s, vf0.s, oA0, 0,0,0);
    oA1 = __builtin_amdgcn_mfma_f32_16x16x32_bf16(pfA.s, vf1.s, oA1, 0,0,0);
    oB0 = __builtin_amdgcn_mfma_f32_16x16x32_bf16(pfB.s, vf0.s, oB0, 0,0,0);
    oB1 = __builtin_amdgcn_mfma_f32_16x16x32_bf16(pfB.s, vf1.s, oB1, 0,0,0);
  }
  #pragma unroll
  for (int r = 0; r < 4; r++){
    #pragma unroll
    for (int m = 1; m < 16; m <<= 1){
      denA[r] += __shfl_xor(denA[r], m);
      denB[r] += __shfl_xor(denB[r], m);
    }
  }
  // stage normalized attn out (bf16) in s_out[q][c]
  {
    u16* so = &s_out[wv][0][0];
    #pragma unroll
    for (int r = 0; r < 4; r++){
      const int q = quad*4 + r;
      const float iA = 1.f/denA[r], iB = 1.f/denB[r];
      so[q*36 + l15]           = f2b(oA0[r]*iA);
      so[q*36 + 16 + l15]      = f2b(oA1[r]*iA);
      so[(q+16)*36 + l15]      = f2b(oB0[r]*iB);
      so[(q+16)*36 + 16 + l15] = f2b(oB1[r]*iB);
    }
  }
  // LePE per lane: channel lc, 16 x-positions qh*16..qh*16+15 of image row y
  {
    const int lc = lane & 31, qh = lane >> 5;
    float lep[16];
    const float lbias = lb[h*32 + lc];
    #pragma unroll
    for (int i = 0; i < 16; i++) lep[i] = lbias;
    const float* lwc = lw + (size_t)(h*32 + lc)*25;
    #pragma unroll
    for (int ky = 0; ky < 5; ky++){
      const u32* vr = (const u32*)&vstage[wv + ky][lc][0];
      float vv[20];
      #pragma unroll
      for (int jj = 0; jj < 10; jj++){
        u32 pk = vr[qh*8 + jj];
        vv[2*jj]   = pklo(pk);
        vv[2*jj+1] = pkhi(pk);
      }
      const float w0 = lwc[ky*5+0], w1 = lwc[ky*5+1], w2 = lwc[ky*5+2],
                  w3 = lwc[ky*5+3], w4 = lwc[ky*5+4];
      #pragma unroll
      for (int i = 0; i < 16; i++)
        lep[i] += w0*vv[i] + w1*vv[i+1] + w2*vv[i+2] + w3*vv[i+3] + w4*vv[i+4];
    }
    u16* tb = tt + ((size_t)(b*NN + q0))*NC + h*32;
    const u16* so = &s_out[wv][0][0];
    #pragma unroll
    for (int i = 0; i < 16; i++){
      const int q = qh*16 + i;
      tb[(size_t)q*NC + lc] = f2b(b2f(so[q*36 + lc]) + lep[i]);
    }
  }
}

// K4: out = Wp @ t + bias via MFMA, B-frags direct from tt[b,n,c] bf16.
__global__ void __launch_bounds__(256) k_proj(const u16* __restrict__ wpb,
                                              const u16* __restrict__ tt,
                                              const float* __restrict__ pbias,
                                              float* __restrict__ out){
  const int ot = blockIdx.x, nt = blockIdx.y, b = blockIdx.z;
  const int o0 = ot*32;
  const int tid = threadIdx.x, wv = tid>>6, lane = tid&63;
  const int l15 = lane&15, quad = lane>>4;
  const int n0w = nt*256 + wv*64;
  __shared__ u16 swp[32][264];
  #pragma unroll
  for (int i = 0; i < 4; i++){
    const int flat = i*256 + tid;
    const int row = flat >> 5, col = flat & 31;
    *(uint4*)&swp[row][col*8] = *(const uint4*)(wpb + (size_t)(o0+row)*NC + col*8);
  }
  __syncthreads();
  f32x4 acc[2][4];
  #pragma unroll
  for (int mt = 0; mt < 2; mt++)
    #pragma unroll
    for (int nt2 = 0; nt2 < 4; nt2++) acc[mt][nt2] = (f32x4){0.f,0.f,0.f,0.f};
  const u16* tb = tt + ((size_t)(b*NN + n0w))*NC;
  for (int k0 = 0; k0 < 256; k0 += 32){
    FR af[2], bf[4];
    af[0].u = *(uint4*)&swp[l15][k0 + quad*8];
    af[1].u = *(uint4*)&swp[16+l15][k0 + quad*8];
    #pragma unroll
    for (int nt2 = 0; nt2 < 4; nt2++)
      bf[nt2].u = *(const uint4*)(tb + (size_t)(nt2*16+l15)*NC + k0 + quad*8);
    #pragma unroll
    for (int mt = 0; mt < 2; mt++)
      #pragma unroll
      for (int nt2 = 0; nt2 < 4; nt2++)
        acc[mt][nt2] = __builtin_amdgcn_mfma_f32_16x16x32_bf16(af[mt].s, bf[nt2].s, acc[mt][nt2], 0,0,0);
  }
  float bv[2][4];
  #pragma unroll
  for (int mt = 0; mt < 2; mt++)
    #pragma unroll
    for (int r = 0; r < 4; r++) bv[mt][r] = pbias[o0 + mt*16 + quad*4 + r];
  #pragma unroll
  for (int mt = 0; mt < 2; mt++)
    #pragma unroll
    for (int nt2 = 0; nt2 < 4; nt2++)
      #pragma unroll
      for (int r = 0; r < 4; r++)
        out[(size_t)(b*NC + o0 + mt*16 + quad*4 + r)*NN + n0w + nt2*16 + l15] = acc[mt][nt2][r] + bv[mt][r];
}

extern "C" void kernel_launch(void* const* d_in, const int* in_sizes, int n_in,
                              void* d_out, int out_size, void* d_ws, size_t ws_size,
                              hipStream_t stream){
  const float* x      = (const float*)d_in[0];
  const float* qkv_w  = (const float*)d_in[1];
  const float* proj_w = (const float*)d_in[2];
  const float* proj_b = (const float*)d_in[3];
  const float* lepe_w = (const float*)d_in[4];
  const float* lepe_b = (const float*)d_in[5];
  float* out = (float*)d_out;

  // ws (u16 units): wqb 196608 | wpb 65536 | xt 2M | qt 2M | kt 2M | v 2M | tt 2M
  if (ws_size < (size_t)21495808) return;
  u16* wqb = (u16*)d_ws;
  u16* wpb = wqb + 196608;
  u16* xt  = wpb + 65536;
  u16* qt  = xt + 2097152;
  u16* kt  = qt + 2097152;
  u16* v   = kt + 2097152;
  u16* tt  = v  + 2097152;

  k_cast<<<dim3(512),     256, 0, stream>>>(qkv_w, proj_w, x, wqb, xt);
  k_qkv <<<dim3(24, 4, 8),256, 0, stream>>>(wqb, xt, qt, kt, v);
  k_attn<<<dim3(8, 8, 8), 256, 0, stream>>>(qt, kt, v, lepe_w, lepe_b, tt);
  k_proj<<<dim3(8, 4, 8), 256, 0, stream>>>(wpb, tt, proj_b, out);
}